// Round 8
// baseline (1325.576 us; speedup 1.0000x reference)
//
#include <hip/hip_runtime.h>

#define NN 512
#define NWD 128
#define NSLICES 96                      // B*P*Q
#define NROWS (NSLICES * NN)            // 49152
#define NBLOCKS (NROWS / 4)             // 12288, 128 blocks per slice
#define ALPHA 0.2f

__device__ __forceinline__ float lrelu(float x) {
    return x > 0.f ? x : ALPHA * x;
}

// k0: wa1 = W@a1, wa2 = W@a2 -> global ws (256 floats). 16 blocks x 256.
// Block 0 additionally zeroes the per-slice counters (so no memset dispatch;
// cnt is 0xAA-poisoned by the harness and reused across graph replays).
__global__ __launch_bounds__(256) void wa_kernel(const float* __restrict__ W,
                                                 const float* __restrict__ a,
                                                 float* __restrict__ wa,
                                                 int* __restrict__ cnt) {
    const int t = threadIdx.x;
    const int wid = t >> 6;
    const int lane = t & 63;
    const int l5 = lane & 31;
    const int half = lane >> 5;

    if (blockIdx.x == 0 && t < NSLICES) cnt[t] = 0;

    const int k = (blockIdx.x * 4 + wid) * 2;      // W row pair (k, k+1)
    const float4 a1v = *reinterpret_cast<const float4*>(a + l5 * 4);
    const float4 a2v = *reinterpret_cast<const float4*>(a + NWD + l5 * 4);
    const float4 wv  = *reinterpret_cast<const float4*>(W + (long)k * NWD + lane * 4);

    float p1 = wv.x * a1v.x + wv.y * a1v.y + wv.z * a1v.z + wv.w * a1v.w;
    float p2 = wv.x * a2v.x + wv.y * a2v.y + wv.z * a2v.z + wv.w * a2v.w;
    #pragma unroll
    for (int off = 16; off > 0; off >>= 1) {
        p1 += __shfl_xor(p1, off);
        p2 += __shfl_xor(p2, off);
    }
    if (l5 == 0) {
        wa[k + half] = p1;              // wa1
        wa[NWD + k + half] = p2;        // wa2
    }
}

// ms: merged s-production + streaming at FULL grid (12288 blocks x 4 waves).
//   Each wave owns one row g: computes s1,s2 via float2-lane dot + 6-round
//   butterfly (all lanes end with the sums; s1 never leaves registers).
//   Publishes s2[g] agent-scope; block bumps cnt[slice]; spins till 128
//   (slice cohort = 128 consecutive blocks -- co-resident under in-order
//   dispatch, protocol proven in R6); then streams demand row -> out.
//   No row-max: |e| <= ~15, exp <= 1.2e6, f32-safe (validated R6/R7).
__global__ __launch_bounds__(256) void ms_kernel(const float* __restrict__ demand,
                                                 const float* __restrict__ st,
                                                 const float* __restrict__ wa,
                                                 float* __restrict__ s2g,
                                                 int* __restrict__ cnt,
                                                 float* __restrict__ out) {
    const int t = threadIdx.x;
    const int wid = t >> 6;
    const int lane = t & 63;

    const long g = (long)blockIdx.x * 4 + wid;   // this wave's row
    const long slice = g >> 9;

    // ---- produce s1 (regs), s2 (publish) for own row ----
    const float2 f  = *reinterpret_cast<const float2*>(st + g * NWD + lane * 2);
    const float2 w1 = *reinterpret_cast<const float2*>(wa + lane * 2);
    const float2 w2 = *reinterpret_cast<const float2*>(wa + NWD + lane * 2);
    float p1 = f.x * w1.x + f.y * w1.y;
    float p2 = f.x * w2.x + f.y * w2.y;
    #pragma unroll
    for (int off = 32; off > 0; off >>= 1) {
        p1 += __shfl_xor(p1, off);
        p2 += __shfl_xor(p2, off);
    }
    const float s1i = p1;                        // all lanes hold it
    if (lane == 0)
        __hip_atomic_store(&s2g[g], p2, __ATOMIC_RELAXED, __HIP_MEMORY_SCOPE_AGENT);

    // ---- publish + slice gate ----
    __syncthreads();
    if (t == 0) {
        __threadfence();
        atomicAdd(&cnt[slice], 1);
        while (__hip_atomic_load(&cnt[slice], __ATOMIC_ACQUIRE,
                                 __HIP_MEMORY_SCOPE_AGENT) < 128) {
            __builtin_amdgcn_s_sleep(2);
        }
    }
    __syncthreads();

    // ---- consume: softmax + demand multiply for own row ----
    const int c0 = lane * 4;
    const int c1 = 256 + lane * 4;
    const float* s2s = s2g + slice * NN;
    float sa[4], sb[4];
    #pragma unroll
    for (int k = 0; k < 4; ++k)
        sa[k] = __hip_atomic_load(&s2s[c0 + k], __ATOMIC_RELAXED, __HIP_MEMORY_SCOPE_AGENT);
    #pragma unroll
    for (int k = 0; k < 4; ++k)
        sb[k] = __hip_atomic_load(&s2s[c1 + k], __ATOMIC_RELAXED, __HIP_MEMORY_SCOPE_AGENT);

    float pv[8];
    #pragma unroll
    for (int k = 0; k < 4; ++k) pv[k] = __expf(lrelu(s1i + sa[k]));
    #pragma unroll
    for (int k = 0; k < 4; ++k) pv[4 + k] = __expf(lrelu(s1i + sb[k]));

    float sum = 0.f;
    #pragma unroll
    for (int k = 0; k < 8; ++k) sum += pv[k];
    #pragma unroll
    for (int off = 32; off > 0; off >>= 1) sum += __shfl_xor(sum, off);
    const float inv = 1.f / sum;

    const float* drow = demand + g * NN;
    const float4 d0 = *reinterpret_cast<const float4*>(drow + c0);
    const float4 d1 = *reinterpret_cast<const float4*>(drow + c1);

    float4 o0, o1;
    o0.x = lrelu(d0.x * pv[0] * inv); o0.y = lrelu(d0.y * pv[1] * inv);
    o0.z = lrelu(d0.z * pv[2] * inv); o0.w = lrelu(d0.w * pv[3] * inv);
    o1.x = lrelu(d1.x * pv[4] * inv); o1.y = lrelu(d1.y * pv[5] * inv);
    o1.z = lrelu(d1.z * pv[6] * inv); o1.w = lrelu(d1.w * pv[7] * inv);

    float* orow = out + g * NN;
    *reinterpret_cast<float4*>(orow + c0) = o0;
    *reinterpret_cast<float4*>(orow + c1) = o1;
}

extern "C" void kernel_launch(void* const* d_in, const int* in_sizes, int n_in,
                              void* d_out, int out_size, void* d_ws, size_t ws_size,
                              hipStream_t stream) {
    const float* demand  = (const float*)d_in[0];
    const float* st_feat = (const float*)d_in[1];
    const float* W       = (const float*)d_in[2];
    const float* a       = (const float*)d_in[3];
    float* out = (float*)d_out;

    float* wa  = (float*)d_ws;                 // 256 floats
    float* s2g = wa + 2 * NWD;                 // NROWS floats
    int*   cnt = (int*)(s2g + NROWS);          // NSLICES ints

    wa_kernel<<<16, 256, 0, stream>>>(W, a, wa, cnt);
    ms_kernel<<<NBLOCKS, 256, 0, stream>>>(demand, st_feat, wa, s2g, cnt, out);
}

// Round 9
// 45.820 us; speedup vs baseline: 28.9301x; 28.9301x over previous
//
#include <hip/hip_runtime.h>

#define NN 512
#define NWD 128
#define NSLICES 96                      // B*P*Q
#define NROWS (NSLICES * NN)            // 49152
#define ALPHA 0.2f

__device__ __forceinline__ float lrelu(float x) {
    return x > 0.f ? x : ALPHA * x;
}

// k0: wa1 = W@a1, wa2 = W@a2 -> global ws (256 floats).
// 16 blocks x 256 threads; each wave does ONE coalesced row-pair butterfly.
__global__ __launch_bounds__(256) void wa_kernel(const float* __restrict__ W,
                                                 const float* __restrict__ a,
                                                 float* __restrict__ wa) {
    const int t = threadIdx.x;
    const int wid = t >> 6;
    const int lane = t & 63;
    const int l5 = lane & 31;
    const int half = lane >> 5;

    const int k = (blockIdx.x * 4 + wid) * 2;      // W row pair (k, k+1)
    const float4 a1v = *reinterpret_cast<const float4*>(a + l5 * 4);
    const float4 a2v = *reinterpret_cast<const float4*>(a + NWD + l5 * 4);
    const float4 wv  = *reinterpret_cast<const float4*>(W + (long)k * NWD + lane * 4);

    float p1 = wv.x * a1v.x + wv.y * a1v.y + wv.z * a1v.z + wv.w * a1v.w;
    float p2 = wv.x * a2v.x + wv.y * a2v.y + wv.z * a2v.z + wv.w * a2v.w;
    #pragma unroll
    for (int off = 16; off > 0; off >>= 1) {
        p1 += __shfl_xor(p1, off);
        p2 += __shfl_xor(p2, off);
    }
    if (l5 == 0) {
        wa[k + half] = p1;              // wa1
        wa[NWD + k + half] = p2;        // wa2
    }
}

// k1: s1[g], s2[g] for all rows. 1536 blocks x 32 rows (2x TLP vs R7), and
// all 4 float4 loads per wave issued BEFORE any butterfly (64 B/lane in
// flight) so HBM latency overlaps the dependent shuffle chains.
__global__ __launch_bounds__(256) void s_kernel(const float* __restrict__ st,
                                                const float* __restrict__ wa,
                                                float* __restrict__ s1,
                                                float* __restrict__ s2) {
    const int t = threadIdx.x;
    const int wid = t >> 6;
    const int lane = t & 63;
    const int l5 = lane & 31;
    const int half = lane >> 5;

    const float4 w1v = *reinterpret_cast<const float4*>(wa + l5 * 4);
    const float4 w2v = *reinterpret_cast<const float4*>(wa + NWD + l5 * 4);
    const long blockbase = (long)blockIdx.x * 32;   // 32 rows per block
    const long wavebase = blockbase + (long)wid * 8; // 8 rows = 4 rowpairs per wave

    // prefetch all 4 rowpair loads
    float4 f[4];
    #pragma unroll
    for (int i = 0; i < 4; ++i)
        f[i] = *reinterpret_cast<const float4*>(st + (wavebase + i * 2) * NWD + lane * 4);

    #pragma unroll
    for (int i = 0; i < 4; ++i) {
        float p1 = f[i].x * w1v.x + f[i].y * w1v.y + f[i].z * w1v.z + f[i].w * w1v.w;
        float p2 = f[i].x * w2v.x + f[i].y * w2v.y + f[i].z * w2v.z + f[i].w * w2v.w;
        #pragma unroll
        for (int off = 16; off > 0; off >>= 1) {
            p1 += __shfl_xor(p1, off);
            p2 += __shfl_xor(p2, off);
        }
        if (l5 == 0) {
            const long g = wavebase + i * 2 + half;
            s1[g] = p1;
            s2[g] = p2;
        }
    }
}

// k2: streaming kernel. One wave per row; 8 cols/lane (2x float4).
// No row-max: |e| <= ~15, exp <= 1.2e6 -- f32-safe (validated R6/R7).
__global__ __launch_bounds__(256) void main_kernel(const float* __restrict__ demand,
                                                   const float* __restrict__ s1,
                                                   const float* __restrict__ s2,
                                                   float* __restrict__ out) {
    const int wid = threadIdx.x >> 6;
    const int lane = threadIdx.x & 63;
    const long g = (long)blockIdx.x * 4 + wid;   // global row
    const long slice = g >> 9;
    const float s1i = s1[g];
    const float* s2s = s2 + slice * NN;

    const int c0 = lane * 4;
    const int c1 = 256 + lane * 4;
    const float4 sa = *reinterpret_cast<const float4*>(s2s + c0);
    const float4 sb = *reinterpret_cast<const float4*>(s2s + c1);

    float pv[8];
    pv[0] = __expf(lrelu(s1i + sa.x));
    pv[1] = __expf(lrelu(s1i + sa.y));
    pv[2] = __expf(lrelu(s1i + sa.z));
    pv[3] = __expf(lrelu(s1i + sa.w));
    pv[4] = __expf(lrelu(s1i + sb.x));
    pv[5] = __expf(lrelu(s1i + sb.y));
    pv[6] = __expf(lrelu(s1i + sb.z));
    pv[7] = __expf(lrelu(s1i + sb.w));

    float sum = 0.f;
    #pragma unroll
    for (int k = 0; k < 8; ++k) sum += pv[k];
    #pragma unroll
    for (int off = 32; off > 0; off >>= 1) sum += __shfl_xor(sum, off);
    const float inv = 1.f / sum;

    const float* drow = demand + g * NN;
    const float4 d0 = *reinterpret_cast<const float4*>(drow + c0);
    const float4 d1 = *reinterpret_cast<const float4*>(drow + c1);

    float4 o0, o1;
    o0.x = lrelu(d0.x * pv[0] * inv); o0.y = lrelu(d0.y * pv[1] * inv);
    o0.z = lrelu(d0.z * pv[2] * inv); o0.w = lrelu(d0.w * pv[3] * inv);
    o1.x = lrelu(d1.x * pv[4] * inv); o1.y = lrelu(d1.y * pv[5] * inv);
    o1.z = lrelu(d1.z * pv[6] * inv); o1.w = lrelu(d1.w * pv[7] * inv);

    float* orow = out + g * NN;
    *reinterpret_cast<float4*>(orow + c0) = o0;
    *reinterpret_cast<float4*>(orow + c1) = o1;
}

extern "C" void kernel_launch(void* const* d_in, const int* in_sizes, int n_in,
                              void* d_out, int out_size, void* d_ws, size_t ws_size,
                              hipStream_t stream) {
    const float* demand  = (const float*)d_in[0];
    const float* st_feat = (const float*)d_in[1];
    const float* W       = (const float*)d_in[2];
    const float* a       = (const float*)d_in[3];
    float* out = (float*)d_out;

    float* wa = (float*)d_ws;                  // 256 floats
    float* s1 = wa + 2 * NWD;                  // NROWS floats
    float* s2 = s1 + NROWS;                    // NROWS floats

    wa_kernel<<<16, 256, 0, stream>>>(W, a, wa);
    s_kernel<<<NROWS / 32, 256, 0, stream>>>(st_feat, wa, s1, s2);
    main_kernel<<<NROWS / 4, 256, 0, stream>>>(demand, s1, s2, out);
}